// Round 8
// baseline (213.682 us; speedup 1.0000x reference)
//
#include <hip/hip_runtime.h>
#include <math.h>

// ---------------------------------------------------------------------------
// GNNEncoder: 3x GCNConv(relu) -> sum of layers -> global_mean_pool -> MLP
// CSR via bucketed counting sort (no global atomics). H rows PRESCALED by
// dis[node]; col stores bare src indices (pad -> zero row ZR=N -> no-op).
// Aggs are L2/L3 request-rate bound on random 128B row gathers (pipelining
// and occupancy nulls, r4/r7): keep plain x2-unrolled loop. EVERY layer's
// relu output is pooled inline (block-local LDS segmented reduction over 32
// contiguous sorted-batch nodes -> one f32 atomic per (graph,channel) run,
// on the otherwise-idle wave 3): X1/X2 residual buffers and their 25.6MB of
// traffic are eliminated. head normalizes + MLP.
// ---------------------------------------------------------------------------

typedef short short8 __attribute__((ext_vector_type(8)));
typedef float f32x4 __attribute__((ext_vector_type(4)));

__device__ inline float bf2f(unsigned short h) {
    return __uint_as_float((unsigned)h << 16);
}
__device__ inline unsigned short f2bf(float f) {  // round-to-nearest-even
    unsigned u = __float_as_uint(f);
    return (unsigned short)((u + (0x7FFFu + ((u >> 16) & 1u))) >> 16);
}
__device__ inline void bh8f(short8 u, float4& a, float4& b) {
    a.x = bf2f((unsigned short)u[0]); a.y = bf2f((unsigned short)u[1]);
    a.z = bf2f((unsigned short)u[2]); a.w = bf2f((unsigned short)u[3]);
    b.x = bf2f((unsigned short)u[4]); b.y = bf2f((unsigned short)u[5]);
    b.z = bf2f((unsigned short)u[6]); b.w = bf2f((unsigned short)u[7]);
}
__device__ inline float4 f4add(float4 a, float4 acc) {
    acc.x += a.x; acc.y += a.y; acc.z += a.z; acc.w += a.w;
    return acc;
}

// ---- launch 1: coarse bucket hist (blocks 0..255) + layer-1 MFMA (rest) ----
template <int K>
__global__ __launch_bounds__(256) void k_hist_gemm(const int* __restrict__ dst,
                                                   int* __restrict__ hist, int E, int chunk,
                                                   const float* __restrict__ X,
                                                   const float* __restrict__ W,
                                                   unsigned short* __restrict__ H, int n) {
    __shared__ int hh[256];
    __shared__ short wt[64 * K];
    int t = threadIdx.x;
    if (blockIdx.x < 256) {
        hh[t] = 0;
        __syncthreads();
        int e0 = blockIdx.x * chunk;
        int e1 = min(e0 + chunk, E);
        for (int e = e0 + t; e < e1; e += 256) atomicAdd(&hh[dst[e] >> 8], 1);
        __syncthreads();
        hist[blockIdx.x * 256 + t] = hh[t];
        return;
    }
    // gemm part
    for (int idx = t; idx < 64 * K; idx += 256) {
        int k = idx >> 6, ch = idx & 63;
        wt[ch * K + k] = (short)f2bf(W[idx]);
    }
    __syncthreads();
    int wave = t >> 6, lane = t & 63;
    int q = lane >> 4, l = lane & 15;
    int tile = (blockIdx.x - 256) * 4 + wave;
    if (tile * 16 >= n) return;  // N % 16 == 0
    int node = tile * 16 + l;
    short8 afr[4][K / 32];
#pragma unroll
    for (int mb = 0; mb < 4; mb++)
#pragma unroll
        for (int s = 0; s < K / 32; s++)
            afr[mb][s] = *(const short8*)(wt + (mb * 16 + l) * K + s * 32 + q * 8);
    f32x4 acc[4] = {};
    const float* xr = X + (size_t)node * K + q * 8;
#pragma unroll
    for (int s = 0; s < K / 32; s++) {
        float4 xa = *(const float4*)(xr + s * 32);
        float4 xb = *(const float4*)(xr + s * 32 + 4);
        short8 bfr;
        bfr[0] = (short)f2bf(xa.x); bfr[1] = (short)f2bf(xa.y);
        bfr[2] = (short)f2bf(xa.z); bfr[3] = (short)f2bf(xa.w);
        bfr[4] = (short)f2bf(xb.x); bfr[5] = (short)f2bf(xb.y);
        bfr[6] = (short)f2bf(xb.z); bfr[7] = (short)f2bf(xb.w);
#pragma unroll
        for (int mb = 0; mb < 4; mb++)
            acc[mb] = __builtin_amdgcn_mfma_f32_16x16x32_bf16(afr[mb][s], bfr, acc[mb], 0, 0, 0);
    }
#pragma unroll
    for (int mb = 0; mb < 4; mb++) {
        ushort4 u;
        u.x = f2bf(acc[mb][0]); u.y = f2bf(acc[mb][1]);
        u.z = f2bf(acc[mb][2]); u.w = f2bf(acc[mb][3]);
        ((ushort4*)H)[(size_t)node * 16 + mb * 4 + q] = u;  // ch = mb*16+q*4
    }
}

// block k scans column k of hist over chunk-blocks -> cursorA, tot.
// Side job: zero pooled[PG].
__global__ void kA_colscan(const int* __restrict__ hist, int* __restrict__ cursorA,
                           int* __restrict__ tot, float* __restrict__ pooled, int PG) {
    __shared__ int s[256];
    int t = threadIdx.x;
    int k = blockIdx.x;
    int v = hist[t * 256 + k];
    s[t] = v;
    __syncthreads();
    for (int st = 1; st < 256; st <<= 1) {
        int u = s[t];
        if (t >= st) u += s[t - st];
        __syncthreads();
        s[t] = u;
        __syncthreads();
    }
    cursorA[t * 256 + k] = s[t] - v;
    if (t == 255) tot[k] = s[255];
    for (int i = k * 256 + t; i < PG; i += 65536) pooled[i] = 0.f;
}

// scatter packed (dstLow<<24 | src) into bucket-contiguous ebuf
__global__ void kA_scatter(const int* __restrict__ src, const int* __restrict__ dst,
                           const int* __restrict__ cursorA, const int* __restrict__ tot,
                           unsigned* __restrict__ ebuf, int E, int chunk) {
    __shared__ int s[256];
    __shared__ int cur[256];
    int t = threadIdx.x;
    s[t] = tot[t];
    __syncthreads();
    for (int st = 1; st < 256; st <<= 1) {
        int u = s[t];
        if (t >= st) u += s[t - st];
        __syncthreads();
        s[t] = u;
        __syncthreads();
    }
    int bstart = (t == 0) ? 0 : s[t - 1];
    cur[t] = cursorA[blockIdx.x * 256 + t] + bstart;
    __syncthreads();
    int e0 = blockIdx.x * chunk;
    int e1 = min(e0 + chunk, E);
    for (int e = e0 + t; e < e1; e += 256) {
        int d = dst[e];
        int p = atomicAdd(&cur[d >> 8], 1);
        ebuf[p] = ((unsigned)(d & 255) << 24) | (unsigned)src[e];
    }
}

// kB: per-bucket degree -> dis + PACKED padded offs (start<<9 | cp, start
// 16B-aligned), scatter bare src into padded windows, fill pads with ZR,
// prescale this bucket's Hb rows by dis, zero ZR rows.
__global__ void kB(const unsigned* __restrict__ ebuf, const int* __restrict__ tot,
                   float* __restrict__ dis, int* __restrict__ offsP,
                   unsigned* __restrict__ col, unsigned short* __restrict__ Hb,
                   unsigned short* __restrict__ Hb2, int N, int ZR) {
    __shared__ int s[256];
    __shared__ int h[256];
    __shared__ int cur[256];
    __shared__ float sdis[256];
    int t = threadIdx.x;
    int k = blockIdx.x;
    s[t] = tot[t];
    __syncthreads();
    for (int st = 1; st < 256; st <<= 1) {
        int u = s[t];
        if (t >= st) u += s[t - st];
        __syncthreads();
        s[t] = u;
        __syncthreads();
    }
    int lo = (k == 0) ? 0 : s[k - 1];
    int hi = s[k];
    int padbase = ((lo + 3) & ~3) + 768 * k;  // aligned: every window start %4==0
    h[t] = 0;
    __syncthreads();
    for (int p = lo + t; p < hi; p += 256) atomicAdd(&h[ebuf[p] >> 24], 1);
    __syncthreads();
    int c = h[t];
    int cp = (c + 3) & ~3;  // padded to multiple of 4
    int node = k * 256 + t;
    float dn = rsqrtf((float)(c + 1));  // +1 self-loop
    sdis[t] = dn;
    if (node < N) dis[node] = dn;
    s[t] = cp;
    __syncthreads();
    for (int st = 1; st < 256; st <<= 1) {
        int u = s[t];
        if (t >= st) u += s[t - st];
        __syncthreads();
        s[t] = u;
        __syncthreads();
    }
    int start = padbase + s[t] - cp;
    if (node < N) offsP[node] = (start << 9) | cp;
    cur[t] = start;
    __syncthreads();
    for (int p = lo + t; p < hi; p += 256) {
        unsigned e = ebuf[p];
        int q = atomicAdd(&cur[e >> 24], 1);
        col[q] = e & 0x00FFFFFFu;  // bare src index
    }
    __syncthreads();
    if (node < N) {
        int end = start + cp;
        for (int q = cur[t]; q < end; q++) col[q] = (unsigned)ZR;  // pad -> zero row
    }
    // prescale this bucket's Hb rows: Hb'[n] = dis[n] * Hb[n]
    for (int idx = t; idx < 2048; idx += 256) {
        int nl = idx >> 3, cs = idx & 7;
        int nd = k * 256 + nl;
        if (nd >= N) continue;
        float d2 = sdis[nl];
        short8 v = ((const short8*)Hb)[(size_t)nd * 8 + cs];
        float4 a, b;
        bh8f(v, a, b);
        short8 o;
        o[0] = (short)f2bf(a.x * d2); o[1] = (short)f2bf(a.y * d2);
        o[2] = (short)f2bf(a.z * d2); o[3] = (short)f2bf(a.w * d2);
        o[4] = (short)f2bf(b.x * d2); o[5] = (short)f2bf(b.y * d2);
        o[6] = (short)f2bf(b.z * d2); o[7] = (short)f2bf(b.w * d2);
        ((short8*)Hb)[(size_t)nd * 8 + cs] = o;
    }
    if (k == 0) {  // zero rows used by pad entries
        if (t < 32) ((unsigned*)Hb)[(size_t)ZR * 32 + t] = 0u;
        else if (t < 64) ((unsigned*)Hb2)[(size_t)ZR * 32 + (t - 32)] = 0u;
    }
}

// ---- FUSED agg + inline pooling + next-layer transform (layers 1,2) -------
// 32 nodes/block. Agg (plain x2-unrolled gather), relu -> f32 rows into LDS
// sm + bf16 rows into vbuf. Then wave 0-1: MFMA transform -> Hout (prescaled
// by dis); wave 3: segmented pool flush of this layer's x into pooled.
__global__ __launch_bounds__(256) void k_aggemm(const unsigned short* __restrict__ H,
                                                const unsigned* __restrict__ col,
                                                const int* __restrict__ offsP,
                                                const float* __restrict__ dis,
                                                const float* __restrict__ bias,
                                                const float* __restrict__ W,
                                                const int* __restrict__ batch,
                                                float* __restrict__ pooled,
                                                unsigned short* __restrict__ Hout, int n) {
    __shared__ short wt[64 * 64];    // W^T bf16 (8 KB)
    __shared__ short vbuf[32 * 72];  // relu'd bf16 rows for MFMA (+pad)
    __shared__ float sm[32][65];     // relu'd f32 rows for pooling
    __shared__ int sg[32];
    int t = threadIdx.x;
    for (int idx = t; idx < 64 * 64; idx += 256) {
        int k = idx >> 6, ch = idx & 63;
        wt[ch * 64 + k] = (short)f2bf(W[idx]);
    }
    const short8* Hs = (const short8*)H;
    int base = blockIdx.x * 32;
    int cs = t & 7;
    int nl = t >> 3;  // 0..31
    int node = base + nl;
    if (t < 32) sg[t] = (base + t < n) ? batch[base + t] : -1;
    const float4* bias4 = (const float4*)bias;
    float4 bb0 = bias4[cs * 2];
    float4 bb1 = bias4[cs * 2 + 1];
    if (node < n) {
        float dn = dis[node];
        float4 acc0, acc1;
        bh8f(Hs[(size_t)node * 8 + cs], acc0, acc1);  // self term (already *dis)
        int po = offsP[node];
        int p = po >> 9, hiP = p + (po & 511);
        for (; p + 8 <= hiP; p += 8) {
            uint4 ea = *(const uint4*)(col + p);
            uint4 eb = *(const uint4*)(col + p + 4);
            short8 g0 = Hs[(size_t)ea.x * 8 + cs];
            short8 g1 = Hs[(size_t)ea.y * 8 + cs];
            short8 g2 = Hs[(size_t)ea.z * 8 + cs];
            short8 g3 = Hs[(size_t)ea.w * 8 + cs];
            short8 g4 = Hs[(size_t)eb.x * 8 + cs];
            short8 g5 = Hs[(size_t)eb.y * 8 + cs];
            short8 g6 = Hs[(size_t)eb.z * 8 + cs];
            short8 g7 = Hs[(size_t)eb.w * 8 + cs];
            float4 a, b;
            bh8f(g0, a, b); acc0 = f4add(a, acc0); acc1 = f4add(b, acc1);
            bh8f(g1, a, b); acc0 = f4add(a, acc0); acc1 = f4add(b, acc1);
            bh8f(g2, a, b); acc0 = f4add(a, acc0); acc1 = f4add(b, acc1);
            bh8f(g3, a, b); acc0 = f4add(a, acc0); acc1 = f4add(b, acc1);
            bh8f(g4, a, b); acc0 = f4add(a, acc0); acc1 = f4add(b, acc1);
            bh8f(g5, a, b); acc0 = f4add(a, acc0); acc1 = f4add(b, acc1);
            bh8f(g6, a, b); acc0 = f4add(a, acc0); acc1 = f4add(b, acc1);
            bh8f(g7, a, b); acc0 = f4add(a, acc0); acc1 = f4add(b, acc1);
        }
        if (p < hiP) {
            uint4 e4 = *(const uint4*)(col + p);
            short8 g0 = Hs[(size_t)e4.x * 8 + cs];
            short8 g1 = Hs[(size_t)e4.y * 8 + cs];
            short8 g2 = Hs[(size_t)e4.z * 8 + cs];
            short8 g3 = Hs[(size_t)e4.w * 8 + cs];
            float4 a, b;
            bh8f(g0, a, b); acc0 = f4add(a, acc0); acc1 = f4add(b, acc1);
            bh8f(g1, a, b); acc0 = f4add(a, acc0); acc1 = f4add(b, acc1);
            bh8f(g2, a, b); acc0 = f4add(a, acc0); acc1 = f4add(b, acc1);
            bh8f(g3, a, b); acc0 = f4add(a, acc0); acc1 = f4add(b, acc1);
        }
        float4 v0, v1;
        v0.x = fmaxf(acc0.x * dn + bb0.x, 0.f);
        v0.y = fmaxf(acc0.y * dn + bb0.y, 0.f);
        v0.z = fmaxf(acc0.z * dn + bb0.z, 0.f);
        v0.w = fmaxf(acc0.w * dn + bb0.w, 0.f);
        v1.x = fmaxf(acc1.x * dn + bb1.x, 0.f);
        v1.y = fmaxf(acc1.y * dn + bb1.y, 0.f);
        v1.z = fmaxf(acc1.z * dn + bb1.z, 0.f);
        v1.w = fmaxf(acc1.w * dn + bb1.w, 0.f);
        short8 o;
        o[0] = (short)f2bf(v0.x); o[1] = (short)f2bf(v0.y);
        o[2] = (short)f2bf(v0.z); o[3] = (short)f2bf(v0.w);
        o[4] = (short)f2bf(v1.x); o[5] = (short)f2bf(v1.y);
        o[6] = (short)f2bf(v1.z); o[7] = (short)f2bf(v1.w);
        *(short8*)(vbuf + nl * 72 + cs * 8) = o;
        float* r = &sm[nl][cs * 8];
        r[0] = v0.x; r[1] = v0.y; r[2] = v0.z; r[3] = v0.w;
        r[4] = v1.x; r[5] = v1.y; r[6] = v1.z; r[7] = v1.w;
    }
    __syncthreads();
    int wave = t >> 6, lane = t & 63;
    if (wave == 3) {  // pooling flush: channel c walks 32 nodes, one atomic/run
        int c = t - 192;
        float acc = 0.f;
        int cg = -1;
        for (int i = 0; i < 32; i++) {
            int g = sg[i];
            if (g != cg) {
                if (cg >= 0) atomicAdd(&pooled[(size_t)cg * 64 + c], acc);
                cg = g;
                acc = 0.f;
            }
            if (g >= 0) acc += sm[i][c];
        }
        if (cg >= 0) atomicAdd(&pooled[(size_t)cg * 64 + c], acc);
        return;
    }
    if (wave >= 2) return;
    // MFMA transform of this block's 32 nodes (2 waves x 16-node tiles)
    int q = lane >> 4, l = lane & 15;
    if (base + wave * 16 >= n) return;  // N % 16 == 0
    int mnode = base + wave * 16 + l;
    float dn2 = dis[mnode];  // prescale next-layer H row
    short8 afr[4][2];
#pragma unroll
    for (int mb = 0; mb < 4; mb++)
#pragma unroll
        for (int s = 0; s < 2; s++)
            afr[mb][s] = *(const short8*)(wt + (mb * 16 + l) * 64 + s * 32 + q * 8);
    f32x4 acc[4] = {};
#pragma unroll
    for (int s = 0; s < 2; s++) {
        short8 bfr = *(const short8*)(vbuf + (wave * 16 + l) * 72 + s * 32 + q * 8);
#pragma unroll
        for (int mb = 0; mb < 4; mb++)
            acc[mb] = __builtin_amdgcn_mfma_f32_16x16x32_bf16(afr[mb][s], bfr, acc[mb], 0, 0, 0);
    }
#pragma unroll
    for (int mb = 0; mb < 4; mb++) {
        ushort4 u;
        u.x = f2bf(acc[mb][0] * dn2); u.y = f2bf(acc[mb][1] * dn2);
        u.z = f2bf(acc[mb][2] * dn2); u.w = f2bf(acc[mb][3] * dn2);
        ((ushort4*)Hout)[(size_t)mnode * 16 + mb * 4 + q] = u;
    }
}

// Final aggregation (layer 3) + BLOCK-LOCAL segmented pooling (no residuals:
// x1,x2 were pooled inline by the aggemm kernels).
__global__ __launch_bounds__(256) void k_agg3pool(const unsigned short* __restrict__ H,
                                                  const unsigned* __restrict__ col,
                                                  const int* __restrict__ offsP,
                                                  const float* __restrict__ dis,
                                                  const float* __restrict__ bias,
                                                  const int* __restrict__ batch,
                                                  float* __restrict__ pooled, int n) {
    __shared__ float sm[32][65];  // [node_local][channel], +1 pad
    __shared__ int sg[32];
    int t = threadIdx.x;
    int base = blockIdx.x * 32;
    int nl = t >> 3, lane = t & 7;
    int node = base + nl;
    if (t < 32) sg[t] = (base + t < n) ? batch[base + t] : -1;
    if (node < n) {
        const short8* Hs = (const short8*)H;
        float dn = dis[node];
        float4 acc0, acc1;
        bh8f(Hs[(size_t)node * 8 + lane], acc0, acc1);
        int po = offsP[node];
        int p = po >> 9, hiP = p + (po & 511);
        for (; p + 8 <= hiP; p += 8) {
            uint4 ea = *(const uint4*)(col + p);
            uint4 eb = *(const uint4*)(col + p + 4);
            short8 g0 = Hs[(size_t)ea.x * 8 + lane];
            short8 g1 = Hs[(size_t)ea.y * 8 + lane];
            short8 g2 = Hs[(size_t)ea.z * 8 + lane];
            short8 g3 = Hs[(size_t)ea.w * 8 + lane];
            short8 g4 = Hs[(size_t)eb.x * 8 + lane];
            short8 g5 = Hs[(size_t)eb.y * 8 + lane];
            short8 g6 = Hs[(size_t)eb.z * 8 + lane];
            short8 g7 = Hs[(size_t)eb.w * 8 + lane];
            float4 a, b;
            bh8f(g0, a, b); acc0 = f4add(a, acc0); acc1 = f4add(b, acc1);
            bh8f(g1, a, b); acc0 = f4add(a, acc0); acc1 = f4add(b, acc1);
            bh8f(g2, a, b); acc0 = f4add(a, acc0); acc1 = f4add(b, acc1);
            bh8f(g3, a, b); acc0 = f4add(a, acc0); acc1 = f4add(b, acc1);
            bh8f(g4, a, b); acc0 = f4add(a, acc0); acc1 = f4add(b, acc1);
            bh8f(g5, a, b); acc0 = f4add(a, acc0); acc1 = f4add(b, acc1);
            bh8f(g6, a, b); acc0 = f4add(a, acc0); acc1 = f4add(b, acc1);
            bh8f(g7, a, b); acc0 = f4add(a, acc0); acc1 = f4add(b, acc1);
        }
        if (p < hiP) {
            uint4 e4 = *(const uint4*)(col + p);
            short8 g0 = Hs[(size_t)e4.x * 8 + lane];
            short8 g1 = Hs[(size_t)e4.y * 8 + lane];
            short8 g2 = Hs[(size_t)e4.z * 8 + lane];
            short8 g3 = Hs[(size_t)e4.w * 8 + lane];
            float4 a, b;
            bh8f(g0, a, b); acc0 = f4add(a, acc0); acc1 = f4add(b, acc1);
            bh8f(g1, a, b); acc0 = f4add(a, acc0); acc1 = f4add(b, acc1);
            bh8f(g2, a, b); acc0 = f4add(a, acc0); acc1 = f4add(b, acc1);
            bh8f(g3, a, b); acc0 = f4add(a, acc0); acc1 = f4add(b, acc1);
        }
        const float4* bias4 = (const float4*)bias;
        float4 bb0 = bias4[lane * 2];
        float4 bb1 = bias4[lane * 2 + 1];
        float* r = &sm[nl][lane * 8];
        r[0] = fmaxf(acc0.x * dn + bb0.x, 0.f);
        r[1] = fmaxf(acc0.y * dn + bb0.y, 0.f);
        r[2] = fmaxf(acc0.z * dn + bb0.z, 0.f);
        r[3] = fmaxf(acc0.w * dn + bb0.w, 0.f);
        r[4] = fmaxf(acc1.x * dn + bb1.x, 0.f);
        r[5] = fmaxf(acc1.y * dn + bb1.y, 0.f);
        r[6] = fmaxf(acc1.z * dn + bb1.z, 0.f);
        r[7] = fmaxf(acc1.w * dn + bb1.w, 0.f);
    }
    __syncthreads();
    if (t < 64) {  // thread t = channel t: walk 32 nodes, flush per graph-run
        float acc = 0.f;
        int cg = -1;
        for (int i = 0; i < 32; i++) {
            int g = sg[i];
            if (g != cg) {
                if (cg >= 0) atomicAdd(&pooled[(size_t)cg * 64 + t], acc);
                cg = g;
                acc = 0.f;
            }
            if (g >= 0) acc += sm[i][t];
        }
        if (cg >= 0) atomicAdd(&pooled[(size_t)cg * 64 + t], acc);
    }
}

// one 64-thread block per graph: count via binary search on sorted batch,
// mean-normalize pooled sums, MLP head
__global__ void k_head(const float* __restrict__ pooled, const int* __restrict__ batch,
                       const float* __restrict__ Wp1, const float* __restrict__ bp1,
                       const float* __restrict__ Wp2, const float* __restrict__ bp2,
                       float* __restrict__ out, int n, int G) {
    int g = blockIdx.x;
    int j = threadIdx.x;  // 0..63
    int a = 0, b = n;
    while (a < b) { int m = (a + b) >> 1; if (batch[m] < g) a = m + 1; else b = m; }
    int beg = a;
    b = n;
    while (a < b) { int m = (a + b) >> 1; if (batch[m] < g + 1) a = m + 1; else b = m; }
    int end = a;
    float cnt = (float)(end - beg);
    float p = pooled[(size_t)g * 64 + j] / fmaxf(cnt, 1.f);
    __shared__ float ps[64];
    __shared__ float ts[64];
    ps[j] = p;
    __syncthreads();
    float t1 = bp1[j];
#pragma unroll 8
    for (int k = 0; k < 64; k++) t1 += ps[k] * Wp1[k * 64 + j];
    t1 = fmaxf(t1, 0.f);
    ts[j] = t1;
    __syncthreads();
    if (j < 32) {
        float o = bp2[j];
#pragma unroll 8
        for (int k = 0; k < 64; k++) o += ts[k] * Wp2[k * 32 + j];
        out[(size_t)g * 32 + j] = o;
    }
}

extern "C" void kernel_launch(void* const* d_in, const int* in_sizes, int n_in,
                              void* d_out, int out_size, void* d_ws, size_t ws_size,
                              hipStream_t stream) {
    const float* x   = (const float*)d_in[0];
    const int*   ei  = (const int*)d_in[1];
    const int*   bat = (const int*)d_in[2];
    const float* W1  = (const float*)d_in[3];
    const float* b1  = (const float*)d_in[4];
    const float* W2  = (const float*)d_in[5];
    const float* b2  = (const float*)d_in[6];
    const float* W3  = (const float*)d_in[7];
    const float* b3  = (const float*)d_in[8];
    const float* Wp1 = (const float*)d_in[9];
    const float* bp1 = (const float*)d_in[10];
    const float* Wp2 = (const float*)d_in[11];
    const float* bp2 = (const float*)d_in[12];

    int N = in_sizes[0] / 128;
    int E = in_sizes[1] / 2;
    int G = out_size / 32;
    const int* src = ei;
    const int* dst = ei + E;

    char* w = (char*)d_ws;
    auto alloc = [&](size_t bytes) -> void* {
        void* p = (void*)w;
        w += (bytes + 255) & ~(size_t)255;
        return p;
    };
    int NB = (N + 255) / 256;  // buckets (<=256)
    int ZR = N;                // reserved all-zero H row for pad entries
    int*            offsP   = (int*)alloc((size_t)N * 4);
    unsigned*       col     = (unsigned*)alloc(((size_t)E + 3 * (size_t)N + 2048) * 4);
    float*          dis     = (float*)alloc((size_t)N * 4);
    int*            hist    = (int*)alloc((size_t)256 * 256 * 4);
    int*            cursorA = (int*)alloc((size_t)256 * 256 * 4);
    int*            tot     = (int*)alloc((size_t)256 * 4);
    unsigned*       ebuf    = (unsigned*)alloc((size_t)E * 4);
    unsigned short* Hb      = (unsigned short*)alloc(((size_t)N + 16) * 64 * 2);
    unsigned short* Hb2     = (unsigned short*)alloc(((size_t)N + 16) * 64 * 2);
    float*          pooled  = (float*)alloc((size_t)G * 64 * 4);

    int chunk = (E + 255) / 256;
    int ggemm = ((N >> 4) + 3) / 4;  // 782 for N=50000
    int gfuse = (N + 31) / 32;       // 32 nodes/block -> 1563 blocks
    int gagg  = (N + 31) / 32;

    k_hist_gemm<128><<<256 + ggemm, 256, 0, stream>>>(dst, hist, E, chunk, x, W1, Hb, N);
    kA_colscan<<<256, 256, 0, stream>>>(hist, cursorA, tot, pooled, G * 64);
    kA_scatter<<<256, 256, 0, stream>>>(src, dst, cursorA, tot, ebuf, E, chunk);
    kB<<<NB, 256, 0, stream>>>(ebuf, tot, dis, offsP, col, Hb, Hb2, N, ZR);

    k_aggemm<<<gfuse, 256, 0, stream>>>(Hb, col, offsP, dis, b1, W2, bat, pooled, Hb2, N);
    k_aggemm<<<gfuse, 256, 0, stream>>>(Hb2, col, offsP, dis, b2, W3, bat, pooled, Hb, N);
    k_agg3pool<<<gagg, 256, 0, stream>>>(Hb, col, offsP, dis, b3, bat, pooled, N);

    k_head<<<G, 64, 0, stream>>>(pooled, bat, Wp1, bp1, Wp2, bp2, (float*)d_out, N, G);
}

// Round 9
// 209.599 us; speedup vs baseline: 1.0195x; 1.0195x over previous
//
#include <hip/hip_runtime.h>
#include <math.h>

// ---------------------------------------------------------------------------
// GNNEncoder: 3x GCNConv(relu) -> sum of layers -> global_mean_pool -> MLP
// CSR via bucketed counting sort (no global atomics). H rows PRESCALED by
// dis[node]; col stores bare src indices (pad -> zero row ZR=N -> no-op).
// Separate small launches (cooperative grid.sync measured +150us on gfx950:
// cross-XCD flush + rendezvous -- do NOT fuse phases). Aggs: 32 nodes/block,
// aligned uint4 col loads, x2 unroll. agg3 does block-local segmented
// pooling in LDS (contiguous sorted batch => ~2-3 graphs/block) and flushes
// ONE f32 atomic per (graph,channel) per block (~260K atomics, distinct
// addresses within wave): S buffer round-trip (25.6MB) eliminated.
// MEASURED FLOOR (r3-r8 ledger): the 3 agg passes are random-row L2/L3
// request-rate bound (~2.9 TB/s effective on 102MB/pass); occupancy,
// degree-sort, software-pipelining, and traffic-elimination all null.
// ---------------------------------------------------------------------------

typedef short short8 __attribute__((ext_vector_type(8)));
typedef float f32x4 __attribute__((ext_vector_type(4)));

__device__ inline float bf2f(unsigned short h) {
    return __uint_as_float((unsigned)h << 16);
}
__device__ inline unsigned short f2bf(float f) {  // round-to-nearest-even
    unsigned u = __float_as_uint(f);
    return (unsigned short)((u + (0x7FFFu + ((u >> 16) & 1u))) >> 16);
}
__device__ inline void bh8f(short8 u, float4& a, float4& b) {
    a.x = bf2f((unsigned short)u[0]); a.y = bf2f((unsigned short)u[1]);
    a.z = bf2f((unsigned short)u[2]); a.w = bf2f((unsigned short)u[3]);
    b.x = bf2f((unsigned short)u[4]); b.y = bf2f((unsigned short)u[5]);
    b.z = bf2f((unsigned short)u[6]); b.w = bf2f((unsigned short)u[7]);
}
__device__ inline float4 f4add(float4 a, float4 acc) {
    acc.x += a.x; acc.y += a.y; acc.z += a.z; acc.w += a.w;
    return acc;
}

// ---- launch 1: coarse bucket hist (blocks 0..255) + layer-1 MFMA (rest) ----
template <int K>
__global__ __launch_bounds__(256) void k_hist_gemm(const int* __restrict__ dst,
                                                   int* __restrict__ hist, int E, int chunk,
                                                   const float* __restrict__ X,
                                                   const float* __restrict__ W,
                                                   unsigned short* __restrict__ H, int n) {
    __shared__ int hh[256];
    __shared__ short wt[64 * K];
    int t = threadIdx.x;
    if (blockIdx.x < 256) {
        hh[t] = 0;
        __syncthreads();
        int e0 = blockIdx.x * chunk;
        int e1 = min(e0 + chunk, E);
        for (int e = e0 + t; e < e1; e += 256) atomicAdd(&hh[dst[e] >> 8], 1);
        __syncthreads();
        hist[blockIdx.x * 256 + t] = hh[t];
        return;
    }
    // gemm part
    for (int idx = t; idx < 64 * K; idx += 256) {
        int k = idx >> 6, ch = idx & 63;
        wt[ch * K + k] = (short)f2bf(W[idx]);
    }
    __syncthreads();
    int wave = t >> 6, lane = t & 63;
    int q = lane >> 4, l = lane & 15;
    int tile = (blockIdx.x - 256) * 4 + wave;
    if (tile * 16 >= n) return;  // N % 16 == 0
    int node = tile * 16 + l;
    short8 afr[4][K / 32];
#pragma unroll
    for (int mb = 0; mb < 4; mb++)
#pragma unroll
        for (int s = 0; s < K / 32; s++)
            afr[mb][s] = *(const short8*)(wt + (mb * 16 + l) * K + s * 32 + q * 8);
    f32x4 acc[4] = {};
    const float* xr = X + (size_t)node * K + q * 8;
#pragma unroll
    for (int s = 0; s < K / 32; s++) {
        float4 xa = *(const float4*)(xr + s * 32);
        float4 xb = *(const float4*)(xr + s * 32 + 4);
        short8 bfr;
        bfr[0] = (short)f2bf(xa.x); bfr[1] = (short)f2bf(xa.y);
        bfr[2] = (short)f2bf(xa.z); bfr[3] = (short)f2bf(xa.w);
        bfr[4] = (short)f2bf(xb.x); bfr[5] = (short)f2bf(xb.y);
        bfr[6] = (short)f2bf(xb.z); bfr[7] = (short)f2bf(xb.w);
#pragma unroll
        for (int mb = 0; mb < 4; mb++)
            acc[mb] = __builtin_amdgcn_mfma_f32_16x16x32_bf16(afr[mb][s], bfr, acc[mb], 0, 0, 0);
    }
#pragma unroll
    for (int mb = 0; mb < 4; mb++) {
        ushort4 u;
        u.x = f2bf(acc[mb][0]); u.y = f2bf(acc[mb][1]);
        u.z = f2bf(acc[mb][2]); u.w = f2bf(acc[mb][3]);
        ((ushort4*)H)[(size_t)node * 16 + mb * 4 + q] = u;  // ch = mb*16+q*4
    }
}

// block k scans column k of hist over chunk-blocks -> cursorA, tot.
// Side job: zero pooled[PG] (ready long before agg3's atomics).
__global__ void kA_colscan(const int* __restrict__ hist, int* __restrict__ cursorA,
                           int* __restrict__ tot, float* __restrict__ pooled, int PG) {
    __shared__ int s[256];
    int t = threadIdx.x;
    int k = blockIdx.x;
    int v = hist[t * 256 + k];
    s[t] = v;
    __syncthreads();
    for (int st = 1; st < 256; st <<= 1) {
        int u = s[t];
        if (t >= st) u += s[t - st];
        __syncthreads();
        s[t] = u;
        __syncthreads();
    }
    cursorA[t * 256 + k] = s[t] - v;
    if (t == 255) tot[k] = s[255];
    for (int i = k * 256 + t; i < PG; i += 65536) pooled[i] = 0.f;
}

// scatter packed (dstLow<<24 | src) into bucket-contiguous ebuf
__global__ void kA_scatter(const int* __restrict__ src, const int* __restrict__ dst,
                           const int* __restrict__ cursorA, const int* __restrict__ tot,
                           unsigned* __restrict__ ebuf, int E, int chunk) {
    __shared__ int s[256];
    __shared__ int cur[256];
    int t = threadIdx.x;
    s[t] = tot[t];
    __syncthreads();
    for (int st = 1; st < 256; st <<= 1) {
        int u = s[t];
        if (t >= st) u += s[t - st];
        __syncthreads();
        s[t] = u;
        __syncthreads();
    }
    int bstart = (t == 0) ? 0 : s[t - 1];
    cur[t] = cursorA[blockIdx.x * 256 + t] + bstart;
    __syncthreads();
    int e0 = blockIdx.x * chunk;
    int e1 = min(e0 + chunk, E);
    for (int e = e0 + t; e < e1; e += 256) {
        int d = dst[e];
        int p = atomicAdd(&cur[d >> 8], 1);
        ebuf[p] = ((unsigned)(d & 255) << 24) | (unsigned)src[e];
    }
}

// kB: per-bucket degree -> dis + PACKED padded offs (start<<9 | cp, start
// 16B-aligned), scatter bare src into padded windows, fill pads with ZR,
// prescale this bucket's Hb rows by dis, zero ZR rows.
__global__ void kB(const unsigned* __restrict__ ebuf, const int* __restrict__ tot,
                   float* __restrict__ dis, int* __restrict__ offsP,
                   unsigned* __restrict__ col, unsigned short* __restrict__ Hb,
                   unsigned short* __restrict__ Hb2, int N, int ZR) {
    __shared__ int s[256];
    __shared__ int h[256];
    __shared__ int cur[256];
    __shared__ float sdis[256];
    int t = threadIdx.x;
    int k = blockIdx.x;
    s[t] = tot[t];
    __syncthreads();
    for (int st = 1; st < 256; st <<= 1) {
        int u = s[t];
        if (t >= st) u += s[t - st];
        __syncthreads();
        s[t] = u;
        __syncthreads();
    }
    int lo = (k == 0) ? 0 : s[k - 1];
    int hi = s[k];
    int padbase = ((lo + 3) & ~3) + 768 * k;  // aligned: every window start %4==0
    h[t] = 0;
    __syncthreads();
    for (int p = lo + t; p < hi; p += 256) atomicAdd(&h[ebuf[p] >> 24], 1);
    __syncthreads();
    int c = h[t];
    int cp = (c + 3) & ~3;  // padded to multiple of 4
    int node = k * 256 + t;
    float dn = rsqrtf((float)(c + 1));  // +1 self-loop
    sdis[t] = dn;
    if (node < N) dis[node] = dn;
    s[t] = cp;
    __syncthreads();
    for (int st = 1; st < 256; st <<= 1) {
        int u = s[t];
        if (t >= st) u += s[t - st];
        __syncthreads();
        s[t] = u;
        __syncthreads();
    }
    int start = padbase + s[t] - cp;
    if (node < N) offsP[node] = (start << 9) | cp;
    cur[t] = start;
    __syncthreads();
    for (int p = lo + t; p < hi; p += 256) {
        unsigned e = ebuf[p];
        int q = atomicAdd(&cur[e >> 24], 1);
        col[q] = e & 0x00FFFFFFu;  // bare src index
    }
    __syncthreads();
    if (node < N) {
        int end = start + cp;
        for (int q = cur[t]; q < end; q++) col[q] = (unsigned)ZR;  // pad -> zero row
    }
    // prescale this bucket's Hb rows: Hb'[n] = dis[n] * Hb[n]
    for (int idx = t; idx < 2048; idx += 256) {
        int nl = idx >> 3, cs = idx & 7;
        int nd = k * 256 + nl;
        if (nd >= N) continue;
        float d2 = sdis[nl];
        short8 v = ((const short8*)Hb)[(size_t)nd * 8 + cs];
        float4 a, b;
        bh8f(v, a, b);
        short8 o;
        o[0] = (short)f2bf(a.x * d2); o[1] = (short)f2bf(a.y * d2);
        o[2] = (short)f2bf(a.z * d2); o[3] = (short)f2bf(a.w * d2);
        o[4] = (short)f2bf(b.x * d2); o[5] = (short)f2bf(b.y * d2);
        o[6] = (short)f2bf(b.z * d2); o[7] = (short)f2bf(b.w * d2);
        ((short8*)Hb)[(size_t)nd * 8 + cs] = o;
    }
    if (k == 0) {  // zero rows used by pad entries
        if (t < 32) ((unsigned*)Hb)[(size_t)ZR * 32 + t] = 0u;
        else if (t < 64) ((unsigned*)Hb2)[(size_t)ZR * 32 + (t - 32)] = 0u;
    }
}

// ---- FUSED agg + next-layer transform (layers 1->2 and 2->3) --------------
// 32 nodes/block, one agg round, then 2 waves of 16-node MFMA tiles.
__global__ __launch_bounds__(256) void k_aggemm(const unsigned short* __restrict__ H,
                                                const unsigned* __restrict__ col,
                                                const int* __restrict__ offsP,
                                                const float* __restrict__ dis,
                                                const float* __restrict__ bias,
                                                const float* __restrict__ W,
                                                unsigned short* __restrict__ Xout,
                                                unsigned short* __restrict__ Hout, int n) {
    __shared__ short wt[64 * 64];    // W^T bf16
    __shared__ short vbuf[32 * 72];  // agg output rows, +8 shorts pad
    int t = threadIdx.x;
    for (int idx = t; idx < 64 * 64; idx += 256) {
        int k = idx >> 6, ch = idx & 63;
        wt[ch * 64 + k] = (short)f2bf(W[idx]);
    }
    const short8* Hs = (const short8*)H;
    int base = blockIdx.x * 32;
    int cs = t & 7;
    int nl = t >> 3;  // 0..31
    int node = base + nl;
    const float4* bias4 = (const float4*)bias;
    float4 bb0 = bias4[cs * 2];
    float4 bb1 = bias4[cs * 2 + 1];
    if (node < n) {
        float dn = dis[node];
        float4 acc0, acc1;
        bh8f(Hs[(size_t)node * 8 + cs], acc0, acc1);  // self term (already *dis)
        int po = offsP[node];
        int p = po >> 9, hiP = p + (po & 511);
        for (; p + 8 <= hiP; p += 8) {
            uint4 ea = *(const uint4*)(col + p);
            uint4 eb = *(const uint4*)(col + p + 4);
            short8 g0 = Hs[(size_t)ea.x * 8 + cs];
            short8 g1 = Hs[(size_t)ea.y * 8 + cs];
            short8 g2 = Hs[(size_t)ea.z * 8 + cs];
            short8 g3 = Hs[(size_t)ea.w * 8 + cs];
            short8 g4 = Hs[(size_t)eb.x * 8 + cs];
            short8 g5 = Hs[(size_t)eb.y * 8 + cs];
            short8 g6 = Hs[(size_t)eb.z * 8 + cs];
            short8 g7 = Hs[(size_t)eb.w * 8 + cs];
            float4 a, b;
            bh8f(g0, a, b); acc0 = f4add(a, acc0); acc1 = f4add(b, acc1);
            bh8f(g1, a, b); acc0 = f4add(a, acc0); acc1 = f4add(b, acc1);
            bh8f(g2, a, b); acc0 = f4add(a, acc0); acc1 = f4add(b, acc1);
            bh8f(g3, a, b); acc0 = f4add(a, acc0); acc1 = f4add(b, acc1);
            bh8f(g4, a, b); acc0 = f4add(a, acc0); acc1 = f4add(b, acc1);
            bh8f(g5, a, b); acc0 = f4add(a, acc0); acc1 = f4add(b, acc1);
            bh8f(g6, a, b); acc0 = f4add(a, acc0); acc1 = f4add(b, acc1);
            bh8f(g7, a, b); acc0 = f4add(a, acc0); acc1 = f4add(b, acc1);
        }
        if (p < hiP) {
            uint4 e4 = *(const uint4*)(col + p);
            short8 g0 = Hs[(size_t)e4.x * 8 + cs];
            short8 g1 = Hs[(size_t)e4.y * 8 + cs];
            short8 g2 = Hs[(size_t)e4.z * 8 + cs];
            short8 g3 = Hs[(size_t)e4.w * 8 + cs];
            float4 a, b;
            bh8f(g0, a, b); acc0 = f4add(a, acc0); acc1 = f4add(b, acc1);
            bh8f(g1, a, b); acc0 = f4add(a, acc0); acc1 = f4add(b, acc1);
            bh8f(g2, a, b); acc0 = f4add(a, acc0); acc1 = f4add(b, acc1);
            bh8f(g3, a, b); acc0 = f4add(a, acc0); acc1 = f4add(b, acc1);
        }
        float4 v0, v1;
        v0.x = fmaxf(acc0.x * dn + bb0.x, 0.f);
        v0.y = fmaxf(acc0.y * dn + bb0.y, 0.f);
        v0.z = fmaxf(acc0.z * dn + bb0.z, 0.f);
        v0.w = fmaxf(acc0.w * dn + bb0.w, 0.f);
        v1.x = fmaxf(acc1.x * dn + bb1.x, 0.f);
        v1.y = fmaxf(acc1.y * dn + bb1.y, 0.f);
        v1.z = fmaxf(acc1.z * dn + bb1.z, 0.f);
        v1.w = fmaxf(acc1.w * dn + bb1.w, 0.f);
        short8 o;
        o[0] = (short)f2bf(v0.x); o[1] = (short)f2bf(v0.y);
        o[2] = (short)f2bf(v0.z); o[3] = (short)f2bf(v0.w);
        o[4] = (short)f2bf(v1.x); o[5] = (short)f2bf(v1.y);
        o[6] = (short)f2bf(v1.z); o[7] = (short)f2bf(v1.w);
        ((short8*)Xout)[(size_t)node * 8 + cs] = o;
        *(short8*)(vbuf + nl * 72 + cs * 8) = o;
    }
    __syncthreads();
    // MFMA transform of this block's 32 nodes (2 waves x 16-node tiles)
    int wave = t >> 6, lane = t & 63;
    if (wave >= 2) return;
    int q = lane >> 4, l = lane & 15;
    if (base + wave * 16 >= n) return;  // N % 16 == 0
    int mnode = base + wave * 16 + l;
    float dn2 = dis[mnode];  // prescale next-layer H row
    short8 afr[4][2];
#pragma unroll
    for (int mb = 0; mb < 4; mb++)
#pragma unroll
        for (int s = 0; s < 2; s++)
            afr[mb][s] = *(const short8*)(wt + (mb * 16 + l) * 64 + s * 32 + q * 8);
    f32x4 acc[4] = {};
#pragma unroll
    for (int s = 0; s < 2; s++) {
        short8 bfr = *(const short8*)(vbuf + (wave * 16 + l) * 72 + s * 32 + q * 8);
#pragma unroll
        for (int mb = 0; mb < 4; mb++)
            acc[mb] = __builtin_amdgcn_mfma_f32_16x16x32_bf16(afr[mb][s], bfr, acc[mb], 0, 0, 0);
    }
#pragma unroll
    for (int mb = 0; mb < 4; mb++) {
        ushort4 u;
        u.x = f2bf(acc[mb][0] * dn2); u.y = f2bf(acc[mb][1] * dn2);
        u.z = f2bf(acc[mb][2] * dn2); u.w = f2bf(acc[mb][3] * dn2);
        ((ushort4*)Hout)[(size_t)mnode * 16 + mb * 4 + q] = u;
    }
}

// Final aggregation (layer 3) + residuals + BLOCK-LOCAL segmented pooling:
// batch is sorted, so 32 contiguous nodes span ~2-3 graphs. Stage per-node
// rows in LDS (padded, conflict-free), then 64 channel-threads walk the 32
// nodes flushing one atomicAdd per (graph,channel) run (~260K atomics total,
// distinct addresses within a wave). Eliminates the 25.6MB S round-trip.
__global__ __launch_bounds__(256) void k_agg3pool(const unsigned short* __restrict__ H,
                                                  const unsigned* __restrict__ col,
                                                  const int* __restrict__ offsP,
                                                  const float* __restrict__ dis,
                                                  const float* __restrict__ bias,
                                                  const unsigned short* __restrict__ add1,
                                                  const unsigned short* __restrict__ add2,
                                                  const int* __restrict__ batch,
                                                  float* __restrict__ pooled, int n) {
    __shared__ float sm[32][65];  // [node_local][channel], +1 pad
    __shared__ int sg[32];
    int t = threadIdx.x;
    int base = blockIdx.x * 32;
    int nl = t >> 3, lane = t & 7;
    int node = base + nl;
    if (t < 32) sg[t] = (base + t < n) ? batch[base + t] : -1;
    if (node < n) {
        const short8* Hs = (const short8*)H;
        float dn = dis[node];
        float4 acc0, acc1;
        bh8f(Hs[(size_t)node * 8 + lane], acc0, acc1);
        int po = offsP[node];
        int p = po >> 9, hiP = p + (po & 511);
        for (; p + 8 <= hiP; p += 8) {
            uint4 ea = *(const uint4*)(col + p);
            uint4 eb = *(const uint4*)(col + p + 4);
            short8 g0 = Hs[(size_t)ea.x * 8 + lane];
            short8 g1 = Hs[(size_t)ea.y * 8 + lane];
            short8 g2 = Hs[(size_t)ea.z * 8 + lane];
            short8 g3 = Hs[(size_t)ea.w * 8 + lane];
            short8 g4 = Hs[(size_t)eb.x * 8 + lane];
            short8 g5 = Hs[(size_t)eb.y * 8 + lane];
            short8 g6 = Hs[(size_t)eb.z * 8 + lane];
            short8 g7 = Hs[(size_t)eb.w * 8 + lane];
            float4 a, b;
            bh8f(g0, a, b); acc0 = f4add(a, acc0); acc1 = f4add(b, acc1);
            bh8f(g1, a, b); acc0 = f4add(a, acc0); acc1 = f4add(b, acc1);
            bh8f(g2, a, b); acc0 = f4add(a, acc0); acc1 = f4add(b, acc1);
            bh8f(g3, a, b); acc0 = f4add(a, acc0); acc1 = f4add(b, acc1);
            bh8f(g4, a, b); acc0 = f4add(a, acc0); acc1 = f4add(b, acc1);
            bh8f(g5, a, b); acc0 = f4add(a, acc0); acc1 = f4add(b, acc1);
            bh8f(g6, a, b); acc0 = f4add(a, acc0); acc1 = f4add(b, acc1);
            bh8f(g7, a, b); acc0 = f4add(a, acc0); acc1 = f4add(b, acc1);
        }
        if (p < hiP) {
            uint4 e4 = *(const uint4*)(col + p);
            short8 g0 = Hs[(size_t)e4.x * 8 + lane];
            short8 g1 = Hs[(size_t)e4.y * 8 + lane];
            short8 g2 = Hs[(size_t)e4.z * 8 + lane];
            short8 g3 = Hs[(size_t)e4.w * 8 + lane];
            float4 a, b;
            bh8f(g0, a, b); acc0 = f4add(a, acc0); acc1 = f4add(b, acc1);
            bh8f(g1, a, b); acc0 = f4add(a, acc0); acc1 = f4add(b, acc1);
            bh8f(g2, a, b); acc0 = f4add(a, acc0); acc1 = f4add(b, acc1);
            bh8f(g3, a, b); acc0 = f4add(a, acc0); acc1 = f4add(b, acc1);
        }
        const float4* bias4 = (const float4*)bias;
        float4 bb0 = bias4[lane * 2];
        float4 bb1 = bias4[lane * 2 + 1];
        float4 v0, v1;
        v0.x = fmaxf(acc0.x * dn + bb0.x, 0.f);
        v0.y = fmaxf(acc0.y * dn + bb0.y, 0.f);
        v0.z = fmaxf(acc0.z * dn + bb0.z, 0.f);
        v0.w = fmaxf(acc0.w * dn + bb0.w, 0.f);
        v1.x = fmaxf(acc1.x * dn + bb1.x, 0.f);
        v1.y = fmaxf(acc1.y * dn + bb1.y, 0.f);
        v1.z = fmaxf(acc1.z * dn + bb1.z, 0.f);
        v1.w = fmaxf(acc1.w * dn + bb1.w, 0.f);
        size_t slot = (size_t)node * 8 + lane;
        float4 a10, a11, a20, a21;
        bh8f(((const short8*)add1)[slot], a10, a11);
        bh8f(((const short8*)add2)[slot], a20, a21);
        v0.x += a10.x + a20.x; v0.y += a10.y + a20.y;
        v0.z += a10.z + a20.z; v0.w += a10.w + a20.w;
        v1.x += a11.x + a21.x; v1.y += a11.y + a21.y;
        v1.z += a11.z + a21.z; v1.w += a11.w + a21.w;
        float* r = &sm[nl][lane * 8];
        r[0] = v0.x; r[1] = v0.y; r[2] = v0.z; r[3] = v0.w;
        r[4] = v1.x; r[5] = v1.y; r[6] = v1.z; r[7] = v1.w;
    }
    __syncthreads();
    if (t < 64) {  // thread t = channel t: walk 32 nodes, flush per graph-run
        float acc = 0.f;
        int cg = -1;
        for (int i = 0; i < 32; i++) {
            int g = sg[i];
            if (g != cg) {
                if (cg >= 0) atomicAdd(&pooled[(size_t)cg * 64 + t], acc);
                cg = g;
                acc = 0.f;
            }
            if (g >= 0) acc += sm[i][t];
        }
        if (cg >= 0) atomicAdd(&pooled[(size_t)cg * 64 + t], acc);
    }
}

// one 64-thread block per graph: count via binary search on sorted batch,
// mean-normalize pooled sums, MLP head
__global__ void k_head(const float* __restrict__ pooled, const int* __restrict__ batch,
                       const float* __restrict__ Wp1, const float* __restrict__ bp1,
                       const float* __restrict__ Wp2, const float* __restrict__ bp2,
                       float* __restrict__ out, int n, int G) {
    int g = blockIdx.x;
    int j = threadIdx.x;  // 0..63
    int a = 0, b = n;
    while (a < b) { int m = (a + b) >> 1; if (batch[m] < g) a = m + 1; else b = m; }
    int beg = a;
    b = n;
    while (a < b) { int m = (a + b) >> 1; if (batch[m] < g + 1) a = m + 1; else b = m; }
    int end = a;
    float cnt = (float)(end - beg);
    float p = pooled[(size_t)g * 64 + j] / fmaxf(cnt, 1.f);
    __shared__ float ps[64];
    __shared__ float ts[64];
    ps[j] = p;
    __syncthreads();
    float t1 = bp1[j];
#pragma unroll 8
    for (int k = 0; k < 64; k++) t1 += ps[k] * Wp1[k * 64 + j];
    t1 = fmaxf(t1, 0.f);
    ts[j] = t1;
    __syncthreads();
    if (j < 32) {
        float o = bp2[j];
#pragma unroll 8
        for (int k = 0; k < 64; k++) o += ts[k] * Wp2[k * 32 + j];
        out[(size_t)g * 32 + j] = o;
    }
}

extern "C" void kernel_launch(void* const* d_in, const int* in_sizes, int n_in,
                              void* d_out, int out_size, void* d_ws, size_t ws_size,
                              hipStream_t stream) {
    const float* x   = (const float*)d_in[0];
    const int*   ei  = (const int*)d_in[1];
    const int*   bat = (const int*)d_in[2];
    const float* W1  = (const float*)d_in[3];
    const float* b1  = (const float*)d_in[4];
    const float* W2  = (const float*)d_in[5];
    const float* b2  = (const float*)d_in[6];
    const float* W3  = (const float*)d_in[7];
    const float* b3  = (const float*)d_in[8];
    const float* Wp1 = (const float*)d_in[9];
    const float* bp1 = (const float*)d_in[10];
    const float* Wp2 = (const float*)d_in[11];
    const float* bp2 = (const float*)d_in[12];

    int N = in_sizes[0] / 128;
    int E = in_sizes[1] / 2;
    int G = out_size / 32;
    const int* src = ei;
    const int* dst = ei + E;

    char* w = (char*)d_ws;
    auto alloc = [&](size_t bytes) -> void* {
        void* p = (void*)w;
        w += (bytes + 255) & ~(size_t)255;
        return p;
    };
    int NB = (N + 255) / 256;  // buckets (<=256)
    int ZR = N;                // reserved all-zero H row for pad entries
    int*            offsP   = (int*)alloc((size_t)N * 4);
    unsigned*       col     = (unsigned*)alloc(((size_t)E + 3 * (size_t)N + 2048) * 4);
    float*          dis     = (float*)alloc((size_t)N * 4);
    int*            hist    = (int*)alloc((size_t)256 * 256 * 4);
    int*            cursorA = (int*)alloc((size_t)256 * 256 * 4);
    int*            tot     = (int*)alloc((size_t)256 * 4);
    unsigned*       ebuf    = (unsigned*)alloc((size_t)E * 4);
    unsigned short* Hb      = (unsigned short*)alloc(((size_t)N + 16) * 64 * 2);
    unsigned short* Hb2     = (unsigned short*)alloc(((size_t)N + 16) * 64 * 2);
    unsigned short* X1      = (unsigned short*)alloc((size_t)N * 64 * 2);
    unsigned short* X2      = (unsigned short*)alloc((size_t)N * 64 * 2);
    float*          pooled  = (float*)alloc((size_t)G * 64 * 4);

    int chunk = (E + 255) / 256;
    int ggemm = ((N >> 4) + 3) / 4;  // 782 for N=50000
    int gfuse = (N + 31) / 32;       // 32 nodes/block -> 1563 blocks
    int gagg  = (N + 31) / 32;

    k_hist_gemm<128><<<256 + ggemm, 256, 0, stream>>>(dst, hist, E, chunk, x, W1, Hb, N);
    kA_colscan<<<256, 256, 0, stream>>>(hist, cursorA, tot, pooled, G * 64);
    kA_scatter<<<256, 256, 0, stream>>>(src, dst, cursorA, tot, ebuf, E, chunk);
    kB<<<NB, 256, 0, stream>>>(ebuf, tot, dis, offsP, col, Hb, Hb2, N, ZR);

    k_aggemm<<<gfuse, 256, 0, stream>>>(Hb, col, offsP, dis, b1, W2, X1, Hb2, N);
    k_aggemm<<<gfuse, 256, 0, stream>>>(Hb2, col, offsP, dis, b2, W3, X2, Hb, N);
    k_agg3pool<<<gagg, 256, 0, stream>>>(Hb, col, offsP, dis, b3, X1, X2, bat, pooled, N);

    k_head<<<G, 64, 0, stream>>>(pooled, bat, Wp1, bp1, Wp2, bp2, (float*)d_out, N, G);
}